// Round 4
// baseline (12094.334 us; speedup 1.0000x reference)
//
#include <hip/hip_runtime.h>

// Problem: B=64, S=512, E=512, H=1024, O=1024, all fp32.
// Phase A: wx[b,s,h] = sum_e x[b,s,e]*Ww[h,e] + Wb[h] + bvec[h]   -> written into d_out
// Phase B: h_t = relu(U h_{t-1} + Ub + wx_t); hs overwrites wx in d_out (in place)
// Phase C: y[b,s,o] = sum_h hs[b,s,h]*Vw[o,h] + Vb[o]             -> d_out (via ws staging chunks)

// ---------------- Phase A GEMM: M=32768, K=512, N=1024 ----------------
__global__ __launch_bounds__(256)
void wx_gemm_k(const float* __restrict__ x, const float* __restrict__ Ww,
               const float* __restrict__ Wb, const float* __restrict__ bvec,
               float* __restrict__ out)
{
    __shared__ float As[128][33];
    __shared__ float Bs[128][33];
    const int m0 = blockIdx.x * 128;
    const int n0 = blockIdx.y * 128;
    const int tid = threadIdx.x;
    const int tx = tid & 15;
    const int ty = tid >> 4;
    float acc[8][8];
#pragma unroll
    for (int i = 0; i < 8; ++i)
#pragma unroll
        for (int j = 0; j < 8; ++j) acc[i][j] = 0.f;

    const int sr = tid >> 3;       // 0..31
    const int sc = (tid & 7) * 4;  // 0..28

    for (int k0 = 0; k0 < 512; k0 += 32) {
#pragma unroll
        for (int p = 0; p < 4; ++p) {
            const int r = sr + 32 * p;
            float4 va = *reinterpret_cast<const float4*>(&x[(size_t)(m0 + r) * 512 + k0 + sc]);
            As[r][sc + 0] = va.x; As[r][sc + 1] = va.y; As[r][sc + 2] = va.z; As[r][sc + 3] = va.w;
            float4 vb = *reinterpret_cast<const float4*>(&Ww[(size_t)(n0 + r) * 512 + k0 + sc]);
            Bs[r][sc + 0] = vb.x; Bs[r][sc + 1] = vb.y; Bs[r][sc + 2] = vb.z; Bs[r][sc + 3] = vb.w;
        }
        __syncthreads();
#pragma unroll
        for (int k = 0; k < 32; ++k) {
            float a[8], b2[8];
#pragma unroll
            for (int i = 0; i < 8; ++i) a[i] = As[ty * 8 + i][k];
#pragma unroll
            for (int j = 0; j < 8; ++j) b2[j] = Bs[tx * 8 + j][k];
#pragma unroll
            for (int i = 0; i < 8; ++i)
#pragma unroll
                for (int j = 0; j < 8; ++j) acc[i][j] += a[i] * b2[j];
        }
        __syncthreads();
    }
    float bias[8];
#pragma unroll
    for (int j = 0; j < 8; ++j) {
        const int n = n0 + tx * 8 + j;
        bias[j] = Wb[n] + bvec[n];
    }
#pragma unroll
    for (int i = 0; i < 8; ++i) {
        const size_t m = (size_t)(m0 + ty * 8 + i);
        float4 o0, o1;
        o0.x = acc[i][0] + bias[0]; o0.y = acc[i][1] + bias[1];
        o0.z = acc[i][2] + bias[2]; o0.w = acc[i][3] + bias[3];
        o1.x = acc[i][4] + bias[4]; o1.y = acc[i][5] + bias[5];
        o1.z = acc[i][6] + bias[6]; o1.w = acc[i][7] + bias[7];
        *reinterpret_cast<float4*>(&out[m * 1024 + n0 + tx * 8])     = o0;
        *reinterpret_cast<float4*>(&out[m * 1024 + n0 + tx * 8 + 4]) = o1;
    }
}

// ---------------- Phase B: persistent recurrence ----------------
// 256 blocks x 512 threads. bgrp = blockIdx&7 (XCD-local group under round-robin
// dispatch), islice = blockIdx>>3. Block owns rows [islice*32, +32) for batches
// [bgrp*8, +8). Thread: kt = tid&31 (k-lane, owns k in {4kt..4kt+3} + 128j),
// rg = tid>>5 -> 2 rows. U register-resident (64 VGPR). Per step: stage 8 h-rows
// (32KB LDS), float4 dots, butterfly-reduce over 32 kt lanes, kt<8 writes batch kt.
__global__ __launch_bounds__(512, 1)
void recur_k(const float* __restrict__ h0, const float* __restrict__ Uw,
             const float* __restrict__ Ub, float* __restrict__ wx_hs,
             float* __restrict__ hA, float* __restrict__ hB,
             unsigned int* __restrict__ bars)
{
    __shared__ float hlds[8 * 1024];
    const int tid = threadIdx.x;
    const int kt = tid & 31;
    const int rg = tid >> 5;                 // 0..15
    const int bgrp = blockIdx.x & 7;         // XCD-local group (perf heuristic only)
    const int islice = blockIdx.x >> 3;      // 0..31
    const int row0 = islice * 32 + rg * 2;

    // U register-resident, contiguous-4 layout: u[4j+c] = Uw[row][kt*4 + 128*j + c]
    float u0[32], u1[32];
#pragma unroll
    for (int j = 0; j < 8; ++j) {
        float4 a = *reinterpret_cast<const float4*>(&Uw[(size_t)(row0 + 0) * 1024 + kt * 4 + 128 * j]);
        u0[4 * j + 0] = a.x; u0[4 * j + 1] = a.y; u0[4 * j + 2] = a.z; u0[4 * j + 3] = a.w;
        float4 c = *reinterpret_cast<const float4*>(&Uw[(size_t)(row0 + 1) * 1024 + kt * 4 + 128 * j]);
        u1[4 * j + 0] = c.x; u1[4 * j + 1] = c.y; u1[4 * j + 2] = c.z; u1[4 * j + 3] = c.w;
    }
    const float ub0 = Ub[row0];
    const float ub1 = Ub[row0 + 1];

    unsigned int* cnt = bars + bgrp * 64;    // one cacheline per group
    const int bglob = bgrp * 8 + kt;         // batch handled at write time (kt<8)

    for (int t = 0; t < 512; ++t) {
        const float* src;
        if (t == 0)       src = h0 + (size_t)bgrp * 8 * 1024;
        else if (t & 1)   src = hA + (size_t)bgrp * 8 * 1024;   // t odd reads hA (written at t-1 even)
        else              src = hB + (size_t)bgrp * 8 * 1024;

        // prefetch wx for this step (lanes kt<8)
        float2 wxv = make_float2(0.f, 0.f);
        if (kt < 8)
            wxv = *reinterpret_cast<const float2*>(&wx_hs[((size_t)bglob * 512 + t) * 1024 + row0]);

        // stage 8 rows of h (8192 floats) into LDS: 512 thr * 4 float4
        {
            const float4* s4 = reinterpret_cast<const float4*>(src);
            float4* d4 = reinterpret_cast<float4*>(hlds);
#pragma unroll
            for (int p = 0; p < 4; ++p) d4[tid + 512 * p] = s4[tid + 512 * p];
        }
        __syncthreads();

        float acc0[8], acc1[8];
#pragma unroll
        for (int b = 0; b < 8; ++b) { acc0[b] = 0.f; acc1[b] = 0.f; }
#pragma unroll
        for (int j = 0; j < 8; ++j) {
#pragma unroll
            for (int b = 0; b < 8; ++b) {
                const float4 hv = *reinterpret_cast<const float4*>(&hlds[b * 1024 + kt * 4 + 128 * j]);
                acc0[b] = fmaf(u0[4 * j + 0], hv.x,
                          fmaf(u0[4 * j + 1], hv.y,
                          fmaf(u0[4 * j + 2], hv.z,
                          fmaf(u0[4 * j + 3], hv.w, acc0[b]))));
                acc1[b] = fmaf(u1[4 * j + 0], hv.x,
                          fmaf(u1[4 * j + 1], hv.y,
                          fmaf(u1[4 * j + 2], hv.z,
                          fmaf(u1[4 * j + 3], hv.w, acc1[b]))));
            }
        }
        // butterfly reduce over the 32 kt lanes (xor masks stay within 32-lane halves)
#pragma unroll
        for (int b = 0; b < 8; ++b) {
#pragma unroll
            for (int m = 1; m < 32; m <<= 1) {
                acc0[b] += __shfl_xor(acc0[b], m, 64);
                acc1[b] += __shfl_xor(acc1[b], m, 64);
            }
        }
        // lane kt<8 selects its batch's sums (compile-time indices only: rule #20)
        float sel0 = acc0[0], sel1 = acc1[0];
#pragma unroll
        for (int b = 1; b < 8; ++b) {
            if (kt == b) { sel0 = acc0[b]; sel1 = acc1[b]; }
        }
        if (kt < 8) {
            const float v0 = fmaxf(sel0 + ub0 + wxv.x, 0.f);
            const float v1 = fmaxf(sel1 + ub1 + wxv.y, 0.f);
            float2 vv = make_float2(v0, v1);
            *reinterpret_cast<float2*>(&wx_hs[((size_t)bglob * 512 + t) * 1024 + row0]) = vv;
            float* wt = (t & 1) ? hB : hA;
            *reinterpret_cast<float2*>(&wt[(size_t)bglob * 1024 + row0]) = vv;
        }
        // group barrier: monotonic counter, 32 blocks per group
        __syncthreads();   // drains vmcnt: all this block's stores complete
        if (tid == 0) {
            __threadfence();                                  // release (L2 writeback)
            atomicAdd(cnt, 1u);
            const unsigned int target = 32u * (unsigned)(t + 1);
            while (__hip_atomic_load(cnt, __ATOMIC_RELAXED, __HIP_MEMORY_SCOPE_AGENT) < target) {
                __builtin_amdgcn_s_sleep(1);
            }
            __threadfence();                                  // acquire (L1/L2 inv)
        }
        __syncthreads();
    }
}

// ---------------- Phase C staging copy: hs chunk -> ws ----------------
__global__ void copy_hs_k(const float* __restrict__ hs, float* __restrict__ stg,
                          int s0, int lgcs)
{
    const int cs = 1 << lgcs;
    const size_t n4 = (size_t)64 * cs * 1024 / 4;
    for (size_t i = (size_t)blockIdx.x * blockDim.x + threadIdx.x; i < n4;
         i += (size_t)gridDim.x * blockDim.x) {
        const size_t r = i >> 8;          // row (1024 floats = 256 float4 per row)
        const int c4 = (int)(i & 255);
        const int b = (int)(r >> lgcs);
        const int si = (int)(r & (cs - 1));
        reinterpret_cast<float4*>(stg)[i] =
            reinterpret_cast<const float4*>(&hs[((size_t)b * 512 + s0 + si) * 1024])[c4];
    }
}

// ---------------- Phase C GEMM: Mc=64*cs, K=1024, N=1024, remapped C rows ----------------
__global__ __launch_bounds__(256)
void y_gemm_k(const float* __restrict__ stg, const float* __restrict__ Vw,
              const float* __restrict__ Vb, float* __restrict__ out,
              int s0, int lgcs)
{
    __shared__ float As[128][33];
    __shared__ float Bs[128][33];
    const int m0 = blockIdx.x * 128;
    const int n0 = blockIdx.y * 128;
    const int tid = threadIdx.x;
    const int tx = tid & 15;
    const int ty = tid >> 4;
    const int cs = 1 << lgcs;
    float acc[8][8];
#pragma unroll
    for (int i = 0; i < 8; ++i)
#pragma unroll
        for (int j = 0; j < 8; ++j) acc[i][j] = 0.f;

    const int sr = tid >> 3;
    const int sc = (tid & 7) * 4;

    for (int k0 = 0; k0 < 1024; k0 += 32) {
#pragma unroll
        for (int p = 0; p < 4; ++p) {
            const int r = sr + 32 * p;
            float4 va = *reinterpret_cast<const float4*>(&stg[(size_t)(m0 + r) * 1024 + k0 + sc]);
            As[r][sc + 0] = va.x; As[r][sc + 1] = va.y; As[r][sc + 2] = va.z; As[r][sc + 3] = va.w;
            float4 vb = *reinterpret_cast<const float4*>(&Vw[(size_t)(n0 + r) * 1024 + k0 + sc]);
            Bs[r][sc + 0] = vb.x; Bs[r][sc + 1] = vb.y; Bs[r][sc + 2] = vb.z; Bs[r][sc + 3] = vb.w;
        }
        __syncthreads();
#pragma unroll
        for (int k = 0; k < 32; ++k) {
            float a[8], b2[8];
#pragma unroll
            for (int i = 0; i < 8; ++i) a[i] = As[ty * 8 + i][k];
#pragma unroll
            for (int j = 0; j < 8; ++j) b2[j] = Bs[tx * 8 + j][k];
#pragma unroll
            for (int i = 0; i < 8; ++i)
#pragma unroll
                for (int j = 0; j < 8; ++j) acc[i][j] += a[i] * b2[j];
        }
        __syncthreads();
    }
    float bias[8];
#pragma unroll
    for (int j = 0; j < 8; ++j) bias[j] = Vb[n0 + tx * 8 + j];
#pragma unroll
    for (int i = 0; i < 8; ++i) {
        const int m = m0 + ty * 8 + i;       // staging row
        const int b = m >> lgcs;
        const int si = m & (cs - 1);
        const size_t orow = (size_t)b * 512 + s0 + si;
        float4 o0, o1;
        o0.x = acc[i][0] + bias[0]; o0.y = acc[i][1] + bias[1];
        o0.z = acc[i][2] + bias[2]; o0.w = acc[i][3] + bias[3];
        o1.x = acc[i][4] + bias[4]; o1.y = acc[i][5] + bias[5];
        o1.z = acc[i][6] + bias[6]; o1.w = acc[i][7] + bias[7];
        *reinterpret_cast<float4*>(&out[orow * 1024 + n0 + tx * 8])     = o0;
        *reinterpret_cast<float4*>(&out[orow * 1024 + n0 + tx * 8 + 4]) = o1;
    }
}

extern "C" void kernel_launch(void* const* d_in, const int* in_sizes, int n_in,
                              void* d_out, int out_size, void* d_ws, size_t ws_size,
                              hipStream_t stream)
{
    const float* x   = (const float*)d_in[0];  // [64,512,512]
    const float* h0  = (const float*)d_in[1];  // [64,1024]
    const float* Uw  = (const float*)d_in[2];  // [1024,1024]
    const float* Ub  = (const float*)d_in[3];  // [1024]
    const float* Ww  = (const float*)d_in[4];  // [1024,512]
    const float* Wb  = (const float*)d_in[5];  // [1024]
    const float* bv  = (const float*)d_in[6];  // [1024]
    const float* Vw  = (const float*)d_in[7];  // [1024,1024]
    const float* Vb  = (const float*)d_in[8];  // [1024]
    float* out = (float*)d_out;                // reused as wx -> hs -> y

    // ws layout: [staging: 64*cs*1024 f32][hA: 64*1024][hB: 64*1024][barriers: 8*64 u32]
    int lgcs = 6;  // chunk of 64 timesteps preferred
    const size_t fixed = (size_t)2 * 64 * 1024 * 4 + 2048;
    while (lgcs > 1 && ((size_t)64 * (1u << lgcs) * 1024 * 4 + fixed) > ws_size) --lgcs;
    const int cs = 1 << lgcs;
    const size_t stg_elems = (size_t)64 * cs * 1024;

    float* stg = (float*)d_ws;
    float* hA = stg + stg_elems;
    float* hB = hA + 64 * 1024;
    unsigned int* bars = (unsigned int*)(hB + 64 * 1024);

    hipMemsetAsync(bars, 0, 8 * 64 * sizeof(unsigned int), stream);

    // Phase A
    wx_gemm_k<<<dim3(256, 8), 256, 0, stream>>>(x, Ww, Wb, bv, out);
    // Phase B
    recur_k<<<256, 512, 0, stream>>>(h0, Uw, Ub, out, hA, hB, bars);
    // Phase C, chunked to keep the in-place d_out rewrite hazard-free
    for (int s0 = 0; s0 < 512; s0 += cs) {
        copy_hs_k<<<512, 256, 0, stream>>>(out, stg, s0, lgcs);
        y_gemm_k<<<dim3((64 * cs) / 128, 8), 256, 0, stream>>>(stg, Vw, Vb, out, s0, lgcs);
    }
}

// Round 5
// 6281.072 us; speedup vs baseline: 1.9255x; 1.9255x over previous
//
#include <hip/hip_runtime.h>

typedef unsigned long long ull;

// Problem: B=64, S=512, E=512, H=1024, O=1024, all fp32.
// Phase A: wx[b,s,h] = x@Ww^T + Wb + b      -> d_out
// Phase B: h_t = relu(U h_{t-1} + Ub + wx_t); hs overwrites wx in d_out
// Phase C: y = hs@Vw^T + Vb                 -> d_out (via ws staging chunks)

// ---------------- Phase A GEMM: M=32768, K=512, N=1024 ----------------
__global__ __launch_bounds__(256)
void wx_gemm_k(const float* __restrict__ x, const float* __restrict__ Ww,
               const float* __restrict__ Wb, const float* __restrict__ bvec,
               float* __restrict__ out)
{
    __shared__ float As[128][33];
    __shared__ float Bs[128][33];
    const int m0 = blockIdx.x * 128;
    const int n0 = blockIdx.y * 128;
    const int tid = threadIdx.x;
    const int tx = tid & 15;
    const int ty = tid >> 4;
    float acc[8][8];
#pragma unroll
    for (int i = 0; i < 8; ++i)
#pragma unroll
        for (int j = 0; j < 8; ++j) acc[i][j] = 0.f;

    const int sr = tid >> 3;       // 0..31
    const int sc = (tid & 7) * 4;  // 0..28

    for (int k0 = 0; k0 < 512; k0 += 32) {
#pragma unroll
        for (int p = 0; p < 4; ++p) {
            const int r = sr + 32 * p;
            float4 va = *reinterpret_cast<const float4*>(&x[(size_t)(m0 + r) * 512 + k0 + sc]);
            As[r][sc + 0] = va.x; As[r][sc + 1] = va.y; As[r][sc + 2] = va.z; As[r][sc + 3] = va.w;
            float4 vb = *reinterpret_cast<const float4*>(&Ww[(size_t)(n0 + r) * 512 + k0 + sc]);
            Bs[r][sc + 0] = vb.x; Bs[r][sc + 1] = vb.y; Bs[r][sc + 2] = vb.z; Bs[r][sc + 3] = vb.w;
        }
        __syncthreads();
#pragma unroll
        for (int k = 0; k < 32; ++k) {
            float a[8], b2[8];
#pragma unroll
            for (int i = 0; i < 8; ++i) a[i] = As[ty * 8 + i][k];
#pragma unroll
            for (int j = 0; j < 8; ++j) b2[j] = Bs[tx * 8 + j][k];
#pragma unroll
            for (int i = 0; i < 8; ++i)
#pragma unroll
                for (int j = 0; j < 8; ++j) acc[i][j] += a[i] * b2[j];
        }
        __syncthreads();
    }
    float bias[8];
#pragma unroll
    for (int j = 0; j < 8; ++j) {
        const int n = n0 + tx * 8 + j;
        bias[j] = Wb[n] + bvec[n];
    }
#pragma unroll
    for (int i = 0; i < 8; ++i) {
        const size_t m = (size_t)(m0 + ty * 8 + i);
        float4 o0, o1;
        o0.x = acc[i][0] + bias[0]; o0.y = acc[i][1] + bias[1];
        o0.z = acc[i][2] + bias[2]; o0.w = acc[i][3] + bias[3];
        o1.x = acc[i][4] + bias[4]; o1.y = acc[i][5] + bias[5];
        o1.z = acc[i][6] + bias[6]; o1.w = acc[i][7] + bias[7];
        *reinterpret_cast<float4*>(&out[m * 1024 + n0 + tx * 8])     = o0;
        *reinterpret_cast<float4*>(&out[m * 1024 + n0 + tx * 8 + 4]) = o1;
    }
}

// ---------------- Phase B: persistent recurrence, fence-free flag sync ----------------
// 256 blocks x 512 threads. bgrp = blockIdx&7 (group), islice = blockIdx>>3 (member 0..31).
// Block owns rows [islice*32,+32) x full K for batches [bgrp*8,+8); U register-resident.
// Sync per step: relaxed agent-scope (coherent, IF$-homed) data stores -> vmcnt(0) ->
// __syncthreads -> flag[me]=t+1 (coherent). Next step: wave0 polls group's 32 flags with
// one coalesced coherent load until all >= t. NO threadfence => no L2 writeback/invalidate.
__global__ __launch_bounds__(512, 1)
void recur_k(const float* __restrict__ h0, const float* __restrict__ Uw,
             const float* __restrict__ Ub, float* __restrict__ wx_hs,
             float* __restrict__ hA, float* __restrict__ hB,
             unsigned int* __restrict__ flags)
{
    __shared__ float hlds[8 * 1024];
    const int tid = threadIdx.x;
    const int kt = tid & 31;
    const int rg = tid >> 5;                 // 0..15
    const int bgrp = blockIdx.x & 7;         // group (8 batches)
    const int islice = blockIdx.x >> 3;      // member 0..31
    const int row0 = islice * 32 + rg * 2;

    // U register-resident: u[4j+c] = Uw[row][kt*4 + 128*j + c]
    float u0[32], u1[32];
#pragma unroll
    for (int j = 0; j < 8; ++j) {
        float4 a = *reinterpret_cast<const float4*>(&Uw[(size_t)(row0 + 0) * 1024 + kt * 4 + 128 * j]);
        u0[4 * j + 0] = a.x; u0[4 * j + 1] = a.y; u0[4 * j + 2] = a.z; u0[4 * j + 3] = a.w;
        float4 c = *reinterpret_cast<const float4*>(&Uw[(size_t)(row0 + 1) * 1024 + kt * 4 + 128 * j]);
        u1[4 * j + 0] = c.x; u1[4 * j + 1] = c.y; u1[4 * j + 2] = c.z; u1[4 * j + 3] = c.w;
    }
    const float ub0 = Ub[row0];
    const float ub1 = Ub[row0 + 1];

    unsigned int* gflags = flags + bgrp * 32;   // 32 dwords = one 128B line per group
    const int bglob = bgrp * 8 + kt;            // batch written by lane kt<8

    for (int t = 0; t < 512; ++t) {
        // wx prefetch: plain cached load, independent of the flag wait
        float2 wxv = make_float2(0.f, 0.f);
        if (kt < 8)
            wxv = *reinterpret_cast<const float2*>(&wx_hs[((size_t)bglob * 512 + t) * 1024 + row0]);

        // wait until every block in the group finished step t-1
        if (t > 0) {
            if (tid < 64) {
                const unsigned int tgt = (unsigned)t;
                for (;;) {
                    unsigned int f = __hip_atomic_load(&gflags[tid & 31],
                                                       __ATOMIC_RELAXED, __HIP_MEMORY_SCOPE_AGENT);
                    if (__all(f >= tgt)) break;
                    __builtin_amdgcn_s_sleep(1);
                }
            }
            __syncthreads();
        }

        // stage 8 h-rows (32KB) into LDS via agent-coherent 8B loads
        {
            const float* src = (t == 0) ? (h0 + (size_t)bgrp * 8 * 1024)
                                        : (((t & 1) ? hA : hB) + (size_t)bgrp * 8 * 1024);
            const ull* s8 = reinterpret_cast<const ull*>(src);
            ull* d8 = reinterpret_cast<ull*>(hlds);
#pragma unroll
            for (int p = 0; p < 8; ++p)
                d8[tid + 512 * p] = __hip_atomic_load((ull*)&s8[tid + 512 * p],
                                                      __ATOMIC_RELAXED, __HIP_MEMORY_SCOPE_AGENT);
        }
        __syncthreads();

        float acc0[8], acc1[8];
#pragma unroll
        for (int b = 0; b < 8; ++b) { acc0[b] = 0.f; acc1[b] = 0.f; }
#pragma unroll
        for (int j = 0; j < 8; ++j) {
#pragma unroll
            for (int b = 0; b < 8; ++b) {
                const float4 hv = *reinterpret_cast<const float4*>(&hlds[b * 1024 + kt * 4 + 128 * j]);
                acc0[b] = fmaf(u0[4 * j + 0], hv.x,
                          fmaf(u0[4 * j + 1], hv.y,
                          fmaf(u0[4 * j + 2], hv.z,
                          fmaf(u0[4 * j + 3], hv.w, acc0[b]))));
                acc1[b] = fmaf(u1[4 * j + 0], hv.x,
                          fmaf(u1[4 * j + 1], hv.y,
                          fmaf(u1[4 * j + 2], hv.z,
                          fmaf(u1[4 * j + 3], hv.w, acc1[b]))));
            }
        }
        // butterfly reduce over the 32 kt lanes
#pragma unroll
        for (int b = 0; b < 8; ++b) {
#pragma unroll
            for (int m = 1; m < 32; m <<= 1) {
                acc0[b] += __shfl_xor(acc0[b], m, 64);
                acc1[b] += __shfl_xor(acc1[b], m, 64);
            }
        }
        // lane kt<8 selects its batch's sums (compile-time indices only)
        float sel0 = acc0[0], sel1 = acc1[0];
#pragma unroll
        for (int b = 1; b < 8; ++b) {
            if (kt == b) { sel0 = acc0[b]; sel1 = acc1[b]; }
        }
        if (kt < 8) {
            const float v0 = fmaxf(sel0 + ub0 + wxv.x, 0.f);
            const float v1 = fmaxf(sel1 + ub1 + wxv.y, 0.f);
            float2 vv = make_float2(v0, v1);
            // hs trace: plain cached store (consumed by a later kernel)
            *reinterpret_cast<float2*>(&wx_hs[((size_t)bglob * 512 + t) * 1024 + row0]) = vv;
            // exchange buffer: agent-coherent store (IF$-homed)
            float* wt = (t & 1) ? hB : hA;
            ull bits; __builtin_memcpy(&bits, &vv, 8);
            __hip_atomic_store((ull*)&wt[(size_t)bglob * 1024 + row0], bits,
                               __ATOMIC_RELAXED, __HIP_MEMORY_SCOPE_AGENT);
        }
        // publish: all this block's stores complete at coherence point, then bump flag
        asm volatile("s_waitcnt vmcnt(0)" ::: "memory");
        __syncthreads();
        if (tid == 0)
            __hip_atomic_store(&gflags[islice], (unsigned)(t + 1),
                               __ATOMIC_RELAXED, __HIP_MEMORY_SCOPE_AGENT);
    }
}

// ---------------- Phase C staging copy: hs chunk -> ws ----------------
__global__ void copy_hs_k(const float* __restrict__ hs, float* __restrict__ stg,
                          int s0, int lgcs)
{
    const int cs = 1 << lgcs;
    const size_t n4 = (size_t)64 * cs * 1024 / 4;
    for (size_t i = (size_t)blockIdx.x * blockDim.x + threadIdx.x; i < n4;
         i += (size_t)gridDim.x * blockDim.x) {
        const size_t r = i >> 8;          // row (1024 floats = 256 float4 per row)
        const int c4 = (int)(i & 255);
        const int b = (int)(r >> lgcs);
        const int si = (int)(r & (cs - 1));
        reinterpret_cast<float4*>(stg)[i] =
            reinterpret_cast<const float4*>(&hs[((size_t)b * 512 + s0 + si) * 1024])[c4];
    }
}

// ---------------- Phase C GEMM: Mc=64*cs, K=1024, N=1024, remapped C rows ----------------
__global__ __launch_bounds__(256)
void y_gemm_k(const float* __restrict__ stg, const float* __restrict__ Vw,
              const float* __restrict__ Vb, float* __restrict__ out,
              int s0, int lgcs)
{
    __shared__ float As[128][33];
    __shared__ float Bs[128][33];
    const int m0 = blockIdx.x * 128;
    const int n0 = blockIdx.y * 128;
    const int tid = threadIdx.x;
    const int tx = tid & 15;
    const int ty = tid >> 4;
    const int cs = 1 << lgcs;
    float acc[8][8];
#pragma unroll
    for (int i = 0; i < 8; ++i)
#pragma unroll
        for (int j = 0; j < 8; ++j) acc[i][j] = 0.f;

    const int sr = tid >> 3;
    const int sc = (tid & 7) * 4;

    for (int k0 = 0; k0 < 1024; k0 += 32) {
#pragma unroll
        for (int p = 0; p < 4; ++p) {
            const int r = sr + 32 * p;
            float4 va = *reinterpret_cast<const float4*>(&stg[(size_t)(m0 + r) * 1024 + k0 + sc]);
            As[r][sc + 0] = va.x; As[r][sc + 1] = va.y; As[r][sc + 2] = va.z; As[r][sc + 3] = va.w;
            float4 vb = *reinterpret_cast<const float4*>(&Vw[(size_t)(n0 + r) * 1024 + k0 + sc]);
            Bs[r][sc + 0] = vb.x; Bs[r][sc + 1] = vb.y; Bs[r][sc + 2] = vb.z; Bs[r][sc + 3] = vb.w;
        }
        __syncthreads();
#pragma unroll
        for (int k = 0; k < 32; ++k) {
            float a[8], b2[8];
#pragma unroll
            for (int i = 0; i < 8; ++i) a[i] = As[ty * 8 + i][k];
#pragma unroll
            for (int j = 0; j < 8; ++j) b2[j] = Bs[tx * 8 + j][k];
#pragma unroll
            for (int i = 0; i < 8; ++i)
#pragma unroll
                for (int j = 0; j < 8; ++j) acc[i][j] += a[i] * b2[j];
        }
        __syncthreads();
    }
    float bias[8];
#pragma unroll
    for (int j = 0; j < 8; ++j) bias[j] = Vb[n0 + tx * 8 + j];
#pragma unroll
    for (int i = 0; i < 8; ++i) {
        const int m = m0 + ty * 8 + i;       // staging row
        const int b = m >> lgcs;
        const int si = m & (cs - 1);
        const size_t orow = (size_t)b * 512 + s0 + si;
        float4 o0, o1;
        o0.x = acc[i][0] + bias[0]; o0.y = acc[i][1] + bias[1];
        o0.z = acc[i][2] + bias[2]; o0.w = acc[i][3] + bias[3];
        o1.x = acc[i][4] + bias[4]; o1.y = acc[i][5] + bias[5];
        o1.z = acc[i][6] + bias[6]; o1.w = acc[i][7] + bias[7];
        *reinterpret_cast<float4*>(&out[orow * 1024 + n0 + tx * 8])     = o0;
        *reinterpret_cast<float4*>(&out[orow * 1024 + n0 + tx * 8 + 4]) = o1;
    }
}

extern "C" void kernel_launch(void* const* d_in, const int* in_sizes, int n_in,
                              void* d_out, int out_size, void* d_ws, size_t ws_size,
                              hipStream_t stream)
{
    const float* x   = (const float*)d_in[0];  // [64,512,512]
    const float* h0  = (const float*)d_in[1];  // [64,1024]
    const float* Uw  = (const float*)d_in[2];  // [1024,1024]
    const float* Ub  = (const float*)d_in[3];  // [1024]
    const float* Ww  = (const float*)d_in[4];  // [1024,512]
    const float* Wb  = (const float*)d_in[5];  // [1024]
    const float* bv  = (const float*)d_in[6];  // [1024]
    const float* Vw  = (const float*)d_in[7];  // [1024,1024]
    const float* Vb  = (const float*)d_in[8];  // [1024]
    float* out = (float*)d_out;                // reused as wx -> hs -> y

    // ws layout: [staging: 64*cs*1024 f32][hA: 64*1024][hB: 64*1024][flags: 8*32 u32]
    int lgcs = 6;  // chunk of 64 timesteps preferred
    const size_t fixed = (size_t)2 * 64 * 1024 * 4 + 2048;
    while (lgcs > 1 && ((size_t)64 * (1u << lgcs) * 1024 * 4 + fixed) > ws_size) --lgcs;
    const int cs = 1 << lgcs;
    const size_t stg_elems = (size_t)64 * cs * 1024;

    float* stg = (float*)d_ws;
    float* hA = stg + stg_elems;
    float* hB = hA + 64 * 1024;
    unsigned int* flags = (unsigned int*)(hB + 64 * 1024);

    hipMemsetAsync(flags, 0, 8 * 32 * sizeof(unsigned int), stream);

    // Phase A
    wx_gemm_k<<<dim3(256, 8), 256, 0, stream>>>(x, Ww, Wb, bv, out);
    // Phase B
    recur_k<<<256, 512, 0, stream>>>(h0, Uw, Ub, out, hA, hB, flags);
    // Phase C, chunked to keep the in-place d_out rewrite hazard-free
    for (int s0 = 0; s0 < 512; s0 += cs) {
        copy_hs_k<<<512, 256, 0, stream>>>(out, stg, s0, lgcs);
        y_gemm_k<<<dim3((64 * cs) / 128, 8), 256, 0, stream>>>(stg, Vw, Vb, out, s0, lgcs);
    }
}

// Round 6
// 4210.759 us; speedup vs baseline: 2.8722x; 1.4917x over previous
//
#include <hip/hip_runtime.h>

typedef unsigned long long ull;

// Problem: B=64, S=512, E=512, H=1024, O=1024, all fp32.
// Phase A: wx[b,s,h] = x@Ww^T + Wb + b      -> d_out
// Phase B: h_t = relu(U h_{t-1} + Ub + wx_t); hs overwrites wx in d_out
// Phase C: y = hs@Vw^T + Vb                 -> d_out (via ws staging chunks)

// ---------------- Phase A GEMM: M=32768, K=512, N=1024 ----------------
__global__ __launch_bounds__(256)
void wx_gemm_k(const float* __restrict__ x, const float* __restrict__ Ww,
               const float* __restrict__ Wb, const float* __restrict__ bvec,
               float* __restrict__ out)
{
    __shared__ float As[128][33];
    __shared__ float Bs[128][33];
    const int m0 = blockIdx.x * 128;
    const int n0 = blockIdx.y * 128;
    const int tid = threadIdx.x;
    const int tx = tid & 15;
    const int ty = tid >> 4;
    float acc[8][8];
#pragma unroll
    for (int i = 0; i < 8; ++i)
#pragma unroll
        for (int j = 0; j < 8; ++j) acc[i][j] = 0.f;

    const int sr = tid >> 3;       // 0..31
    const int sc = (tid & 7) * 4;  // 0..28

    for (int k0 = 0; k0 < 512; k0 += 32) {
#pragma unroll
        for (int p = 0; p < 4; ++p) {
            const int r = sr + 32 * p;
            float4 va = *reinterpret_cast<const float4*>(&x[(size_t)(m0 + r) * 512 + k0 + sc]);
            As[r][sc + 0] = va.x; As[r][sc + 1] = va.y; As[r][sc + 2] = va.z; As[r][sc + 3] = va.w;
            float4 vb = *reinterpret_cast<const float4*>(&Ww[(size_t)(n0 + r) * 512 + k0 + sc]);
            Bs[r][sc + 0] = vb.x; Bs[r][sc + 1] = vb.y; Bs[r][sc + 2] = vb.z; Bs[r][sc + 3] = vb.w;
        }
        __syncthreads();
#pragma unroll
        for (int k = 0; k < 32; ++k) {
            float a[8], b2[8];
#pragma unroll
            for (int i = 0; i < 8; ++i) a[i] = As[ty * 8 + i][k];
#pragma unroll
            for (int j = 0; j < 8; ++j) b2[j] = Bs[tx * 8 + j][k];
#pragma unroll
            for (int i = 0; i < 8; ++i)
#pragma unroll
                for (int j = 0; j < 8; ++j) acc[i][j] += a[i] * b2[j];
        }
        __syncthreads();
    }
    float bias[8];
#pragma unroll
    for (int j = 0; j < 8; ++j) {
        const int n = n0 + tx * 8 + j;
        bias[j] = Wb[n] + bvec[n];
    }
#pragma unroll
    for (int i = 0; i < 8; ++i) {
        const size_t m = (size_t)(m0 + ty * 8 + i);
        float4 o0, o1;
        o0.x = acc[i][0] + bias[0]; o0.y = acc[i][1] + bias[1];
        o0.z = acc[i][2] + bias[2]; o0.w = acc[i][3] + bias[3];
        o1.x = acc[i][4] + bias[4]; o1.y = acc[i][5] + bias[5];
        o1.z = acc[i][6] + bias[6]; o1.w = acc[i][7] + bias[7];
        *reinterpret_cast<float4*>(&out[m * 1024 + n0 + tx * 8])     = o0;
        *reinterpret_cast<float4*>(&out[m * 1024 + n0 + tx * 8 + 4]) = o1;
    }
}

// ---------------- Phase B: persistent recurrence ----------------
// 256 blocks x 512 threads. gid = blockIdx&15 (group of 16 blocks, same XCD slot
// under round-robin), m = blockIdx>>4 (member 0..15). Group owns batches
// [gid*4,+4); block owns rows [m*64,+64). Thread: kt = tid&31 (k-lane, owns
// k in {kt*4+c + 128*jj}), rt = tid>>5 -> 4 rows. U register-resident (128 VGPR).
// Per step: stage 4 h-rows (16KB LDS), float4 dots (32 ds_read_b128, 16 FMA each),
// LDS transpose-reduce over the 32 kt lanes (no butterfly), even lanes write.
// Sync: fence-free monotonic flags with relaxed agent-scope (coherent) accesses.
__global__ __launch_bounds__(512, 1)
void recur_k(const float* __restrict__ h0, const float* __restrict__ Uw,
             const float* __restrict__ Ub, float* __restrict__ wx_hs,
             float* __restrict__ hA, float* __restrict__ hB,
             unsigned int* __restrict__ flags)
{
    __shared__ float hlds[4 * 1024];      // 16 KB: 4 batches x 1024
    __shared__ float part[32 * 257];      // 32.9 KB: [kt][o] padded 257 (2-way max)
    const int tid = threadIdx.x;
    const int kt = tid & 31;
    const int rt = tid >> 5;              // 0..15
    const int gid = blockIdx.x & 15;      // group
    const int m = blockIdx.x >> 4;        // member 0..15
    const int row0 = m * 64 + rt * 4;     // 4 rows row0..row0+3

    // U register-resident: u[i][4*jj+c] = Uw[row0+i][kt*4 + 128*jj + c]
    float u[4][32];
#pragma unroll
    for (int i = 0; i < 4; ++i)
#pragma unroll
        for (int jj = 0; jj < 8; ++jj) {
            float4 a = *reinterpret_cast<const float4*>(
                &Uw[(size_t)(row0 + i) * 1024 + kt * 4 + 128 * jj]);
            u[i][4 * jj + 0] = a.x; u[i][4 * jj + 1] = a.y;
            u[i][4 * jj + 2] = a.z; u[i][4 * jj + 3] = a.w;
        }

    // writer role: even threads own output o = tid>>1 = b*64 + (rt*4+i)
    const bool wr = (tid & 1) == 0;
    const int o = tid >> 1;               // 0..255
    const int wb = o >> 6;                // batch-local 0..3
    const int wrow = (o & 63) + m * 64;   // global row
    const int wbatch = gid * 4 + wb;      // global batch
    const float ubw = Ub[wrow];
    float* wtrace = &wx_hs[(size_t)wbatch * 512 * 1024 + wrow];   // + t*1024
    const size_t exoff = (size_t)wbatch * 1024 + wrow;

    unsigned int* gflags = flags + gid * 16;   // 16 dwords = 64B line per group

    for (int t = 0; t < 512; ++t) {
        // wx prefetch for this step (plain cached load; own-block rows only)
        float wxv = 0.f;
        if (wr) wxv = wtrace[(size_t)t * 1024];

        // wait until every member finished step t-1
        if (t > 0) {
            if (tid < 64) {
                const unsigned int tgt = (unsigned)t;
                for (;;) {
                    unsigned int f = __hip_atomic_load(&gflags[tid & 15],
                                                       __ATOMIC_RELAXED, __HIP_MEMORY_SCOPE_AGENT);
                    if (__all(f >= tgt)) break;
                    __builtin_amdgcn_s_sleep(1);
                }
            }
            __syncthreads();
        }

        // stage 4 h-rows (16KB) into LDS via agent-coherent 8B loads
        {
            const float* src = (t == 0) ? (h0 + (size_t)gid * 4 * 1024)
                                        : (((t & 1) ? hA : hB) + (size_t)gid * 4 * 1024);
            const ull* s8 = reinterpret_cast<const ull*>(src);
#pragma unroll
            for (int p = 0; p < 4; ++p) {
                ull v = __hip_atomic_load((ull*)&s8[tid + 512 * p],
                                          __ATOMIC_RELAXED, __HIP_MEMORY_SCOPE_AGENT);
                *reinterpret_cast<ull*>(&hlds[2 * (tid + 512 * p)]) = v;
            }
        }
        __syncthreads();

        // dot: 32 ds_read_b128, each feeding 16 FMAs
        float acc[4][4];   // [row i][batch b]
#pragma unroll
        for (int i = 0; i < 4; ++i)
#pragma unroll
            for (int b = 0; b < 4; ++b) acc[i][b] = 0.f;
#pragma unroll
        for (int jj = 0; jj < 8; ++jj)
#pragma unroll
            for (int b = 0; b < 4; ++b) {
                const float4 hv = *reinterpret_cast<const float4*>(
                    &hlds[b * 1024 + kt * 4 + 128 * jj]);
#pragma unroll
                for (int i = 0; i < 4; ++i)
                    acc[i][b] = fmaf(u[i][4 * jj + 0], hv.x,
                                fmaf(u[i][4 * jj + 1], hv.y,
                                fmaf(u[i][4 * jj + 2], hv.z,
                                fmaf(u[i][4 * jj + 3], hv.w, acc[i][b]))));
            }

        // partials -> LDS: part[kt][o'] with o' = b*64 + rt*4 + i  (16 b32, 2-way max)
#pragma unroll
        for (int b = 0; b < 4; ++b)
#pragma unroll
            for (int i = 0; i < 4; ++i)
                part[kt * 257 + b * 64 + rt * 4 + i] = acc[i][b];
        __syncthreads();

        // transpose-reduce: thread (o=tid>>1, sub=tid&1) sums 16 kt's, pair-combine
        float sum = 0.f;
        {
            const int base = 16 * (tid & 1);
#pragma unroll
            for (int i2 = 0; i2 < 16; ++i2)
                sum += part[(base + i2) * 257 + o];
        }
        sum += __shfl_xor(sum, 1, 64);

        if (wr) {
            const float v = fmaxf(sum + ubw + wxv, 0.f);
            wtrace[(size_t)t * 1024] = v;                    // hs trace: plain store
            float* wt = (t & 1) ? hB : hA;                   // exchange: coherent store
            __hip_atomic_store(&wt[exoff], v,
                               __ATOMIC_RELAXED, __HIP_MEMORY_SCOPE_AGENT);
        }
        // publish: drain this block's stores, then bump flag
        asm volatile("s_waitcnt vmcnt(0)" ::: "memory");
        __syncthreads();
        if (tid == 0)
            __hip_atomic_store(&gflags[m], (unsigned)(t + 1),
                               __ATOMIC_RELAXED, __HIP_MEMORY_SCOPE_AGENT);
    }
}

// ---------------- Phase C staging copy: hs chunk -> ws ----------------
__global__ void copy_hs_k(const float* __restrict__ hs, float* __restrict__ stg,
                          int s0, int lgcs)
{
    const int cs = 1 << lgcs;
    const size_t n4 = (size_t)64 * cs * 1024 / 4;
    for (size_t i = (size_t)blockIdx.x * blockDim.x + threadIdx.x; i < n4;
         i += (size_t)gridDim.x * blockDim.x) {
        const size_t r = i >> 8;          // row (1024 floats = 256 float4 per row)
        const int c4 = (int)(i & 255);
        const int b = (int)(r >> lgcs);
        const int si = (int)(r & (cs - 1));
        reinterpret_cast<float4*>(stg)[i] =
            reinterpret_cast<const float4*>(&hs[((size_t)b * 512 + s0 + si) * 1024])[c4];
    }
}

// ---------------- Phase C GEMM: Mc=64*cs, K=1024, N=1024, remapped C rows ----------------
__global__ __launch_bounds__(256)
void y_gemm_k(const float* __restrict__ stg, const float* __restrict__ Vw,
              const float* __restrict__ Vb, float* __restrict__ out,
              int s0, int lgcs)
{
    __shared__ float As[128][33];
    __shared__ float Bs[128][33];
    const int m0 = blockIdx.x * 128;
    const int n0 = blockIdx.y * 128;
    const int tid = threadIdx.x;
    const int tx = tid & 15;
    const int ty = tid >> 4;
    const int cs = 1 << lgcs;
    float acc[8][8];
#pragma unroll
    for (int i = 0; i < 8; ++i)
#pragma unroll
        for (int j = 0; j < 8; ++j) acc[i][j] = 0.f;

    const int sr = tid >> 3;
    const int sc = (tid & 7) * 4;

    for (int k0 = 0; k0 < 1024; k0 += 32) {
#pragma unroll
        for (int p = 0; p < 4; ++p) {
            const int r = sr + 32 * p;
            float4 va = *reinterpret_cast<const float4*>(&stg[(size_t)(m0 + r) * 1024 + k0 + sc]);
            As[r][sc + 0] = va.x; As[r][sc + 1] = va.y; As[r][sc + 2] = va.z; As[r][sc + 3] = va.w;
            float4 vb = *reinterpret_cast<const float4*>(&Vw[(size_t)(n0 + r) * 1024 + k0 + sc]);
            Bs[r][sc + 0] = vb.x; Bs[r][sc + 1] = vb.y; Bs[r][sc + 2] = vb.z; Bs[r][sc + 3] = vb.w;
        }
        __syncthreads();
#pragma unroll
        for (int k = 0; k < 32; ++k) {
            float a[8], b2[8];
#pragma unroll
            for (int i = 0; i < 8; ++i) a[i] = As[ty * 8 + i][k];
#pragma unroll
            for (int j = 0; j < 8; ++j) b2[j] = Bs[tx * 8 + j][k];
#pragma unroll
            for (int i = 0; i < 8; ++i)
#pragma unroll
                for (int j = 0; j < 8; ++j) acc[i][j] += a[i] * b2[j];
        }
        __syncthreads();
    }
    float bias[8];
#pragma unroll
    for (int j = 0; j < 8; ++j) bias[j] = Vb[n0 + tx * 8 + j];
#pragma unroll
    for (int i = 0; i < 8; ++i) {
        const int m = m0 + ty * 8 + i;       // staging row
        const int b = m >> lgcs;
        const int si = m & (cs - 1);
        const size_t orow = (size_t)b * 512 + s0 + si;
        float4 o0, o1;
        o0.x = acc[i][0] + bias[0]; o0.y = acc[i][1] + bias[1];
        o0.z = acc[i][2] + bias[2]; o0.w = acc[i][3] + bias[3];
        o1.x = acc[i][4] + bias[4]; o1.y = acc[i][5] + bias[5];
        o1.z = acc[i][6] + bias[6]; o1.w = acc[i][7] + bias[7];
        *reinterpret_cast<float4*>(&out[orow * 1024 + n0 + tx * 8])     = o0;
        *reinterpret_cast<float4*>(&out[orow * 1024 + n0 + tx * 8 + 4]) = o1;
    }
}

extern "C" void kernel_launch(void* const* d_in, const int* in_sizes, int n_in,
                              void* d_out, int out_size, void* d_ws, size_t ws_size,
                              hipStream_t stream)
{
    const float* x   = (const float*)d_in[0];  // [64,512,512]
    const float* h0  = (const float*)d_in[1];  // [64,1024]
    const float* Uw  = (const float*)d_in[2];  // [1024,1024]
    const float* Ub  = (const float*)d_in[3];  // [1024]
    const float* Ww  = (const float*)d_in[4];  // [1024,512]
    const float* Wb  = (const float*)d_in[5];  // [1024]
    const float* bv  = (const float*)d_in[6];  // [1024]
    const float* Vw  = (const float*)d_in[7];  // [1024,1024]
    const float* Vb  = (const float*)d_in[8];  // [1024]
    float* out = (float*)d_out;                // reused as wx -> hs -> y

    // ws layout: [staging: 64*cs*1024 f32][hA: 64*1024][hB: 64*1024][flags: 16*16 u32]
    int lgcs = 6;  // chunk of 64 timesteps preferred
    const size_t fixed = (size_t)2 * 64 * 1024 * 4 + 2048;
    while (lgcs > 1 && ((size_t)64 * (1u << lgcs) * 1024 * 4 + fixed) > ws_size) --lgcs;
    const int cs = 1 << lgcs;
    const size_t stg_elems = (size_t)64 * cs * 1024;

    float* stg = (float*)d_ws;
    float* hA = stg + stg_elems;
    float* hB = hA + 64 * 1024;
    unsigned int* flags = (unsigned int*)(hB + 64 * 1024);

    hipMemsetAsync(flags, 0, 16 * 16 * sizeof(unsigned int), stream);

    // Phase A
    wx_gemm_k<<<dim3(256, 8), 256, 0, stream>>>(x, Ww, Wb, bv, out);
    // Phase B
    recur_k<<<256, 512, 0, stream>>>(h0, Uw, Ub, out, hA, hB, flags);
    // Phase C, chunked to keep the in-place d_out rewrite hazard-free
    for (int s0 = 0; s0 < 512; s0 += cs) {
        copy_hs_k<<<512, 256, 0, stream>>>(out, stg, s0, lgcs);
        y_gemm_k<<<dim3((64 * cs) / 128, 8), 256, 0, stream>>>(stg, Vw, Vb, out, s0, lgcs);
    }
}

// Round 9
// 2965.007 us; speedup vs baseline: 4.0790x; 1.4202x over previous
//
#include <hip/hip_runtime.h>
#include <hip/hip_bf16.h>

typedef unsigned long long ull;
typedef __attribute__((ext_vector_type(8))) short bf16x8;
typedef __attribute__((ext_vector_type(4))) float f32x4;

// B=64, S=512, E=512, H=1024, O=1024. fp32 in/out.
// A: wx = x@Ww^T + Wb + b -> d_out (fp32 vector GEMM)
// B: h_t = relu(U h + Ub + wx_t); hs overwrites wx in d_out (persistent, flag-sync)
// C: hs -> bf16 (ws), V -> bf16 (ws), y = hs@V^T + Vb via MFMA -> d_out

// ---------------- Phase A GEMM: M=32768, K=512, N=1024 (fp32) ----------------
__global__ __launch_bounds__(256)
void wx_gemm_k(const float* __restrict__ x, const float* __restrict__ Ww,
               const float* __restrict__ Wb, const float* __restrict__ bvec,
               float* __restrict__ out)
{
    __shared__ float As[128][33];
    __shared__ float Bs[128][33];
    const int m0 = blockIdx.x * 128;
    const int n0 = blockIdx.y * 128;
    const int tid = threadIdx.x;
    const int tx = tid & 15;
    const int ty = tid >> 4;
    float acc[8][8];
#pragma unroll
    for (int i = 0; i < 8; ++i)
#pragma unroll
        for (int j = 0; j < 8; ++j) acc[i][j] = 0.f;

    const int sr = tid >> 3;
    const int sc = (tid & 7) * 4;

    for (int k0 = 0; k0 < 512; k0 += 32) {
#pragma unroll
        for (int p = 0; p < 4; ++p) {
            const int r = sr + 32 * p;
            float4 va = *reinterpret_cast<const float4*>(&x[(size_t)(m0 + r) * 512 + k0 + sc]);
            As[r][sc + 0] = va.x; As[r][sc + 1] = va.y; As[r][sc + 2] = va.z; As[r][sc + 3] = va.w;
            float4 vb = *reinterpret_cast<const float4*>(&Ww[(size_t)(n0 + r) * 512 + k0 + sc]);
            Bs[r][sc + 0] = vb.x; Bs[r][sc + 1] = vb.y; Bs[r][sc + 2] = vb.z; Bs[r][sc + 3] = vb.w;
        }
        __syncthreads();
#pragma unroll
        for (int k = 0; k < 32; ++k) {
            float a[8], b2[8];
#pragma unroll
            for (int i = 0; i < 8; ++i) a[i] = As[ty * 8 + i][k];
#pragma unroll
            for (int j = 0; j < 8; ++j) b2[j] = Bs[tx * 8 + j][k];
#pragma unroll
            for (int i = 0; i < 8; ++i)
#pragma unroll
                for (int j = 0; j < 8; ++j) acc[i][j] += a[i] * b2[j];
        }
        __syncthreads();
    }
    float bias[8];
#pragma unroll
    for (int j = 0; j < 8; ++j) {
        const int n = n0 + tx * 8 + j;
        bias[j] = Wb[n] + bvec[n];
    }
#pragma unroll
    for (int i = 0; i < 8; ++i) {
        const size_t m = (size_t)(m0 + ty * 8 + i);
        float4 o0, o1;
        o0.x = acc[i][0] + bias[0]; o0.y = acc[i][1] + bias[1];
        o0.z = acc[i][2] + bias[2]; o0.w = acc[i][3] + bias[3];
        o1.x = acc[i][4] + bias[4]; o1.y = acc[i][5] + bias[5];
        o1.z = acc[i][6] + bias[6]; o1.w = acc[i][7] + bias[7];
        *reinterpret_cast<float4*>(&out[m * 1024 + n0 + tx * 8])     = o0;
        *reinterpret_cast<float4*>(&out[m * 1024 + n0 + tx * 8 + 4]) = o1;
    }
}

// ---------------- Phase B: persistent recurrence (unchanged from r6) ----------------
__global__ __launch_bounds__(512, 1)
void recur_k(const float* __restrict__ h0, const float* __restrict__ Uw,
             const float* __restrict__ Ub, float* __restrict__ wx_hs,
             float* __restrict__ hA, float* __restrict__ hB,
             unsigned int* __restrict__ flags)
{
    __shared__ float hlds[4 * 1024];
    __shared__ float part[32 * 257];
    const int tid = threadIdx.x;
    const int kt = tid & 31;
    const int rt = tid >> 5;
    const int gid = blockIdx.x & 15;
    const int m = blockIdx.x >> 4;
    const int row0 = m * 64 + rt * 4;

    float u[4][32];
#pragma unroll
    for (int i = 0; i < 4; ++i)
#pragma unroll
        for (int jj = 0; jj < 8; ++jj) {
            float4 a = *reinterpret_cast<const float4*>(
                &Uw[(size_t)(row0 + i) * 1024 + kt * 4 + 128 * jj]);
            u[i][4 * jj + 0] = a.x; u[i][4 * jj + 1] = a.y;
            u[i][4 * jj + 2] = a.z; u[i][4 * jj + 3] = a.w;
        }

    const bool wr = (tid & 1) == 0;
    const int o = tid >> 1;
    const int wb = o >> 6;
    const int wrow = (o & 63) + m * 64;
    const int wbatch = gid * 4 + wb;
    const float ubw = Ub[wrow];
    float* wtrace = &wx_hs[(size_t)wbatch * 512 * 1024 + wrow];
    const size_t exoff = (size_t)wbatch * 1024 + wrow;

    unsigned int* gflags = flags + gid * 16;

    for (int t = 0; t < 512; ++t) {
        float wxv = 0.f;
        if (wr) wxv = wtrace[(size_t)t * 1024];

        if (t > 0) {
            if (tid < 64) {
                const unsigned int tgt = (unsigned)t;
                for (;;) {
                    unsigned int f = __hip_atomic_load(&gflags[tid & 15],
                                                       __ATOMIC_RELAXED, __HIP_MEMORY_SCOPE_AGENT);
                    if (__all(f >= tgt)) break;
                    __builtin_amdgcn_s_sleep(1);
                }
            }
            __syncthreads();
        }

        {
            const float* src = (t == 0) ? (h0 + (size_t)gid * 4 * 1024)
                                        : (((t & 1) ? hA : hB) + (size_t)gid * 4 * 1024);
            const ull* s8 = reinterpret_cast<const ull*>(src);
#pragma unroll
            for (int p = 0; p < 4; ++p) {
                ull v = __hip_atomic_load((ull*)&s8[tid + 512 * p],
                                          __ATOMIC_RELAXED, __HIP_MEMORY_SCOPE_AGENT);
                *reinterpret_cast<ull*>(&hlds[2 * (tid + 512 * p)]) = v;
            }
        }
        __syncthreads();

        float acc[4][4];
#pragma unroll
        for (int i = 0; i < 4; ++i)
#pragma unroll
            for (int b = 0; b < 4; ++b) acc[i][b] = 0.f;
#pragma unroll
        for (int jj = 0; jj < 8; ++jj)
#pragma unroll
            for (int b = 0; b < 4; ++b) {
                const float4 hv = *reinterpret_cast<const float4*>(
                    &hlds[b * 1024 + kt * 4 + 128 * jj]);
#pragma unroll
                for (int i = 0; i < 4; ++i)
                    acc[i][b] = fmaf(u[i][4 * jj + 0], hv.x,
                                fmaf(u[i][4 * jj + 1], hv.y,
                                fmaf(u[i][4 * jj + 2], hv.z,
                                fmaf(u[i][4 * jj + 3], hv.w, acc[i][b]))));
            }

#pragma unroll
        for (int b = 0; b < 4; ++b)
#pragma unroll
            for (int i = 0; i < 4; ++i)
                part[kt * 257 + b * 64 + rt * 4 + i] = acc[i][b];
        __syncthreads();

        float sum = 0.f;
        {
            const int base = 16 * (tid & 1);
#pragma unroll
            for (int i2 = 0; i2 < 16; ++i2)
                sum += part[(base + i2) * 257 + o];
        }
        sum += __shfl_xor(sum, 1, 64);

        if (wr) {
            const float v = fmaxf(sum + ubw + wxv, 0.f);
            wtrace[(size_t)t * 1024] = v;
            float* wt = (t & 1) ? hB : hA;
            __hip_atomic_store(&wt[exoff], v,
                               __ATOMIC_RELAXED, __HIP_MEMORY_SCOPE_AGENT);
        }
        asm volatile("s_waitcnt vmcnt(0)" ::: "memory");
        __syncthreads();
        if (tid == 0)
            __hip_atomic_store(&gflags[m], (unsigned)(t + 1),
                               __ATOMIC_RELAXED, __HIP_MEMORY_SCOPE_AGENT);
    }
}

// ---------------- hs (fp32, d_out) -> stg (bf16, ws), row remap b*cs+si ----------------
__global__ void conv_hs_k(const float* __restrict__ hs, unsigned short* __restrict__ stg,
                          int s0, int lgcs)
{
    const int cs = 1 << lgcs;
    const size_t n8 = (size_t)64 * cs * 1024 / 8;
    for (size_t i = (size_t)blockIdx.x * blockDim.x + threadIdx.x; i < n8;
         i += (size_t)gridDim.x * blockDim.x) {
        const size_t r = i >> 7;          // 128 groups of 8 per row
        const int g = (int)(i & 127);
        const int b = (int)(r >> lgcs);
        const int si = (int)(r & (cs - 1));
        const float* src = &hs[((size_t)b * 512 + s0 + si) * 1024 + g * 8];
        const float4 v0 = *reinterpret_cast<const float4*>(src);
        const float4 v1 = *reinterpret_cast<const float4*>(src + 4);
        unsigned short u[8];
        __hip_bfloat16 t0;
        t0 = __float2bfloat16(v0.x); __builtin_memcpy(&u[0], &t0, 2);
        t0 = __float2bfloat16(v0.y); __builtin_memcpy(&u[1], &t0, 2);
        t0 = __float2bfloat16(v0.z); __builtin_memcpy(&u[2], &t0, 2);
        t0 = __float2bfloat16(v0.w); __builtin_memcpy(&u[3], &t0, 2);
        t0 = __float2bfloat16(v1.x); __builtin_memcpy(&u[4], &t0, 2);
        t0 = __float2bfloat16(v1.y); __builtin_memcpy(&u[5], &t0, 2);
        t0 = __float2bfloat16(v1.z); __builtin_memcpy(&u[6], &t0, 2);
        t0 = __float2bfloat16(v1.w); __builtin_memcpy(&u[7], &t0, 2);
        bf16x8 pk; __builtin_memcpy(&pk, u, 16);
        *reinterpret_cast<bf16x8*>(&stg[i * 8]) = pk;
    }
}

// ---------------- Vw (fp32) -> Vbf (bf16) ----------------
__global__ void conv_v_k(const float* __restrict__ Vw, unsigned short* __restrict__ Vbf)
{
    const size_t n8 = (size_t)1024 * 1024 / 8;
    for (size_t i = (size_t)blockIdx.x * blockDim.x + threadIdx.x; i < n8;
         i += (size_t)gridDim.x * blockDim.x) {
        const float4 v0 = *reinterpret_cast<const float4*>(&Vw[i * 8]);
        const float4 v1 = *reinterpret_cast<const float4*>(&Vw[i * 8 + 4]);
        unsigned short u[8];
        __hip_bfloat16 t0;
        t0 = __float2bfloat16(v0.x); __builtin_memcpy(&u[0], &t0, 2);
        t0 = __float2bfloat16(v0.y); __builtin_memcpy(&u[1], &t0, 2);
        t0 = __float2bfloat16(v0.z); __builtin_memcpy(&u[2], &t0, 2);
        t0 = __float2bfloat16(v0.w); __builtin_memcpy(&u[3], &t0, 2);
        t0 = __float2bfloat16(v1.x); __builtin_memcpy(&u[4], &t0, 2);
        t0 = __float2bfloat16(v1.y); __builtin_memcpy(&u[5], &t0, 2);
        t0 = __float2bfloat16(v1.z); __builtin_memcpy(&u[6], &t0, 2);
        t0 = __float2bfloat16(v1.w); __builtin_memcpy(&u[7], &t0, 2);
        bf16x8 pk; __builtin_memcpy(&pk, u, 16);
        *reinterpret_cast<bf16x8*>(&Vbf[i * 8]) = pk;
    }
}

// ---------------- Phase C MFMA GEMM: C[Mc,1024] = stg(bf16) @ Vbf^T + Vb ----------------
// 128x128 tile, BK=64, 256 thr (4 waves, 2x2 of 64x64). Padded LDS [128][72] bf16.
// mfma_f32_16x16x32_bf16; A row = lane&15, k = ks*32+(lane>>4)*8+e; B col = lane&15 (same k).
// D: col = lane&15, row = (lane>>4)*4 + reg  [verified m89/m91].
__global__ __launch_bounds__(256)
void y_gemm_mfma(const unsigned short* __restrict__ stg, const unsigned short* __restrict__ Vbf,
                 const float* __restrict__ Vb, float* __restrict__ out, int s0, int lgcs)
{
    __shared__ unsigned short Al[128 * 72];
    __shared__ unsigned short Bl[128 * 72];
    const int tid = threadIdx.x;
    const int m0 = blockIdx.x * 128;
    const int n0 = blockIdx.y * 128;
    const int lane = tid & 63;
    const int wave = tid >> 6;
    const int wr = wave >> 1, wc = wave & 1;

    f32x4 acc[4][4];
#pragma unroll
    for (int i = 0; i < 4; ++i)
#pragma unroll
        for (int j = 0; j < 4; ++j) acc[i][j] = (f32x4){0.f, 0.f, 0.f, 0.f};

    const int srow = tid >> 3;          // 0..31 (+32p)
    const int sk8 = (tid & 7) * 8;      // bf16 col of 16B piece

    for (int k0 = 0; k0 < 1024; k0 += 64) {
        __syncthreads();
#pragma unroll
        for (int q = 0; q < 4; ++q) {
            const int row = srow + 32 * q;
            *reinterpret_cast<bf16x8*>(&Al[row * 72 + sk8]) =
                *reinterpret_cast<const bf16x8*>(&stg[(size_t)(m0 + row) * 1024 + k0 + sk8]);
            *reinterpret_cast<bf16x8*>(&Bl[row * 72 + sk8]) =
                *reinterpret_cast<const bf16x8*>(&Vbf[(size_t)(n0 + row) * 1024 + k0 + sk8]);
        }
        __syncthreads();
#pragma unroll
        for (int ks = 0; ks < 2; ++ks) {
            const int kcol = ks * 32 + (lane >> 4) * 8;
            bf16x8 af[4], bfr[4];
#pragma unroll
            for (int mt = 0; mt < 4; ++mt)
                af[mt] = *reinterpret_cast<const bf16x8*>(
                    &Al[(wr * 64 + mt * 16 + (lane & 15)) * 72 + kcol]);
#pragma unroll
            for (int nt = 0; nt < 4; ++nt)
                bfr[nt] = *reinterpret_cast<const bf16x8*>(
                    &Bl[(wc * 64 + nt * 16 + (lane & 15)) * 72 + kcol]);
#pragma unroll
            for (int mt = 0; mt < 4; ++mt)
#pragma unroll
                for (int nt = 0; nt < 4; ++nt)
                    acc[mt][nt] = __builtin_amdgcn_mfma_f32_16x16x32_bf16(
                        af[mt], bfr[nt], acc[mt][nt], 0, 0, 0);
        }
    }

    const int cs = 1 << lgcs;
    const int lrow = (lane >> 4) * 4, lcol = lane & 15;
#pragma unroll
    for (int mt = 0; mt < 4; ++mt) {
#pragma unroll
        for (int r = 0; r < 4; ++r) {
            const int mm = m0 + wr * 64 + mt * 16 + lrow + r;
            const int b = mm >> lgcs;
            const int si = mm & (cs - 1);
            float* orow = &out[((size_t)b * 512 + s0 + si) * 1024];
#pragma unroll
            for (int nt = 0; nt < 4; ++nt) {
                const int n = n0 + wc * 64 + nt * 16 + lcol;
                orow[n] = acc[mt][nt][r] + Vb[n];
            }
        }
    }
}

extern "C" void kernel_launch(void* const* d_in, const int* in_sizes, int n_in,
                              void* d_out, int out_size, void* d_ws, size_t ws_size,
                              hipStream_t stream)
{
    const float* x   = (const float*)d_in[0];
    const float* h0  = (const float*)d_in[1];
    const float* Uw  = (const float*)d_in[2];
    const float* Ub  = (const float*)d_in[3];
    const float* Ww  = (const float*)d_in[4];
    const float* Wb  = (const float*)d_in[5];
    const float* bv  = (const float*)d_in[6];
    const float* Vw  = (const float*)d_in[7];
    const float* Vb  = (const float*)d_in[8];
    float* out = (float*)d_out;

    // ws: [stg bf16 64*cs*1024][Vbf bf16 1M][hA f32 64K][hB f32 64K][flags]
    int lgcs = 9;  // prefer whole-S (cs=512): single conv + single big GEMM
    const size_t fixed = (size_t)1024 * 1024 * 2 + (size_t)2 * 64 * 1024 * 4 + 4096;
    while (lgcs > 1 && ((size_t)64 * (1u << lgcs) * 1024 * 2 + fixed) > ws_size) --lgcs;
    const int cs = 1 << lgcs;

    unsigned short* stg = (unsigned short*)d_ws;
    unsigned short* Vbf = stg + (size_t)64 * cs * 1024;
    float* hA = (float*)(Vbf + (size_t)1024 * 1024);
    float* hB = hA + 64 * 1024;
    unsigned int* flags = (unsigned int*)(hB + 64 * 1024);

    hipMemsetAsync(flags, 0, 16 * 16 * sizeof(unsigned int), stream);

    conv_v_k<<<256, 256, 0, stream>>>(Vw, Vbf);
    wx_gemm_k<<<dim3(256, 8), 256, 0, stream>>>(x, Ww, Wb, bv, out);
    recur_k<<<256, 512, 0, stream>>>(h0, Uw, Ub, out, hA, hB, flags);
    for (int s0 = 0; s0 < 512; s0 += cs) {
        conv_hs_k<<<1024, 256, 0, stream>>>(out, stg, s0, lgcs);
        y_gemm_mfma<<<dim3((64 * cs) / 128, 8), 256, 0, stream>>>(stg, Vbf, Vb, out, s0, lgcs);
    }
}